// Round 1
// baseline (3253.657 us; speedup 1.0000x reference)
//
#include <hip/hip_runtime.h>
#include <math.h>

// Problem constants (from reference)
#define DMODEL 1024
#define NHEAD  16
#define HDIM   64
#define SEQ    2048
#define MLPD   8192
#define HALF_MLP 4096
static constexpr float LN_EPS_C = 1e-5f;

// ---------------------------------------------------------------------------
// LayerNorm: one block (256 thr) per row of length DMODEL
// ---------------------------------------------------------------------------
__global__ void ln_kernel(const float* __restrict__ in, float* __restrict__ out) {
    const int row = blockIdx.x;
    const int tid = threadIdx.x;
    __shared__ float rs[256], rs2[256];
    const float* r = in + (size_t)row * DMODEL;
    float s = 0.f, s2 = 0.f;
    for (int i = tid; i < DMODEL; i += 256) {
        float v = r[i];
        s += v; s2 += v * v;
    }
    rs[tid] = s; rs2[tid] = s2;
    __syncthreads();
    for (int off = 128; off > 0; off >>= 1) {
        if (tid < off) { rs[tid] += rs[tid + off]; rs2[tid] += rs2[tid + off]; }
        __syncthreads();
    }
    float mu  = rs[0] * (1.0f / DMODEL);
    float var = rs2[0] * (1.0f / DMODEL) - mu * mu;
    float inv = rsqrtf(var + LN_EPS_C);
    for (int i = tid; i < DMODEL; i += 256)
        out[(size_t)row * DMODEL + i] = (r[i] - mu) * inv;
}

// ---------------------------------------------------------------------------
// GEMM: C[M,N] = A[M,K] * B[N,K]^T (+ residual). A row-major w/ stride lda,
// B row-major w/ stride K (weights), C stride ldc, residual stride ldc.
// Tile 64x64, BK=16, 256 threads, 4x4 per thread. All dims multiples of 64.
// ---------------------------------------------------------------------------
template <bool RES>
__global__ void gemm_bt(const float* __restrict__ A, const float* __restrict__ B,
                        const float* __restrict__ Rsd, float* __restrict__ C,
                        int M, int N, int K, int lda, int ldc) {
    __shared__ float As[16][65];
    __shared__ float Bs[16][65];
    const int n0 = blockIdx.x * 64;
    const int m0 = blockIdx.y * 64;
    const int tid = threadIdx.x;
    const int tx = tid & 15;        // 0..15 -> col group
    const int ty = tid >> 4;        // 0..15 -> row group
    const int lr = tid >> 2;        // 0..63 load row
    const int lc = (tid & 3) * 4;   // 0,4,8,12 load col (k)

    const float* Aptr = A + (size_t)(m0 + lr) * lda;
    const float* Bptr = B + (size_t)(n0 + lr) * K;

    float acc[4][4] = {};

    for (int k0 = 0; k0 < K; k0 += 16) {
        float4 a = *(const float4*)(Aptr + k0 + lc);
        float4 b = *(const float4*)(Bptr + k0 + lc);
        As[lc + 0][lr] = a.x; As[lc + 1][lr] = a.y;
        As[lc + 2][lr] = a.z; As[lc + 3][lr] = a.w;
        Bs[lc + 0][lr] = b.x; Bs[lc + 1][lr] = b.y;
        Bs[lc + 2][lr] = b.z; Bs[lc + 3][lr] = b.w;
        __syncthreads();
#pragma unroll
        for (int k = 0; k < 16; ++k) {
            float av[4], bv[4];
#pragma unroll
            for (int i = 0; i < 4; ++i) av[i] = As[k][ty * 4 + i];
#pragma unroll
            for (int j = 0; j < 4; ++j) bv[j] = Bs[k][tx * 4 + j];
#pragma unroll
            for (int i = 0; i < 4; ++i)
#pragma unroll
                for (int j = 0; j < 4; ++j)
                    acc[i][j] += av[i] * bv[j];
        }
        __syncthreads();
    }

#pragma unroll
    for (int i = 0; i < 4; ++i) {
        const int m = m0 + ty * 4 + i;
#pragma unroll
        for (int j = 0; j < 4; ++j) {
            const int n = n0 + tx * 4 + j;
            float c = acc[i][j];
            if (RES) c += Rsd[(size_t)m * ldc + n];
            C[(size_t)m * ldc + n] = c;
        }
    }
}

// ---------------------------------------------------------------------------
// RoPE in-place on q and k slices of qkv [SEQ, 3*DMODEL].
// One thread per (row, which∈{q,k}, head, pair).
// ---------------------------------------------------------------------------
__global__ void rope_kernel(float* __restrict__ qkv) {
    int idx = blockIdx.x * blockDim.x + threadIdx.x;
    // total = SEQ * 2 * NHEAD * 32
    if (idx >= SEQ * 2 * NHEAD * 32) return;
    const int p     = idx & 31;
    const int h     = (idx >> 5) & 15;
    const int which = (idx >> 9) & 1;        // 0=q, 1=k
    const int row   = idx >> 10;
    float* base = qkv + (size_t)row * (3 * DMODEL) + which * DMODEL + h * HDIM;
    // inv_freq = 10000^(-p/32)
    const float inv_freq = powf(10000.0f, -(float)p / 32.0f);
    const float ang = (float)row * inv_freq;
    const float c = cosf(ang), s = sinf(ang);
    const float x1 = base[p];
    const float x2 = base[p + 32];
    base[p]      = x1 * c - x2 * s;
    base[p + 32] = x2 * c + x1 * s;
}

// ---------------------------------------------------------------------------
// Causal attention: one block (256 thr) per (query row, head).
// Scores for the whole row kept in LDS (<= 8 KB). Two-pass softmax.
// qkv layout: [SEQ, 3*DMODEL]; q at +0, k at +DMODEL, v at +2*DMODEL.
// out: [SEQ, DMODEL] (head-concat layout).
// ---------------------------------------------------------------------------
__global__ void attn_kernel(const float* __restrict__ qkv, float* __restrict__ out) {
    const int row  = blockIdx.x;
    const int head = blockIdx.y;
    const int tid  = threadIdx.x;

    __shared__ float sc[SEQ];        // 8 KB
    __shared__ float qs[HDIM];
    __shared__ float red[256];
    __shared__ float part[4][HDIM];

    const float scale = 0.125f;      // HD^-0.5
    const float* qrow = qkv + (size_t)row * (3 * DMODEL) + head * HDIM;
    if (tid < HDIM) qs[tid] = qrow[tid] * scale;
    __syncthreads();

    const int cnt = row + 1;

    // scores + local max
    float lmax = -INFINITY;
    for (int j = tid; j < cnt; j += 256) {
        const float* krow = qkv + (size_t)j * (3 * DMODEL) + DMODEL + head * HDIM;
        float s = 0.f;
#pragma unroll
        for (int d = 0; d < HDIM; ++d) s += qs[d] * krow[d];
        sc[j] = s;
        lmax = fmaxf(lmax, s);
    }
    red[tid] = lmax;
    __syncthreads();
    for (int off = 128; off > 0; off >>= 1) {
        if (tid < off) red[tid] = fmaxf(red[tid], red[tid + off]);
        __syncthreads();
    }
    const float mx = red[0];
    __syncthreads();

    // exp + local sum
    float lsum = 0.f;
    for (int j = tid; j < cnt; j += 256) {
        float e = __expf(sc[j] - mx);
        sc[j] = e;
        lsum += e;
    }
    red[tid] = lsum;
    __syncthreads();
    for (int off = 128; off > 0; off >>= 1) {
        if (tid < off) red[tid] += red[tid + off];
        __syncthreads();
    }
    const float invsum = 1.0f / red[0];
    __syncthreads();

    // probs @ v : 4 j-groups x 64 dims
    const int d = tid & 63;
    const int g = tid >> 6;
    float acc = 0.f;
    for (int j = g; j < cnt; j += 4)
        acc += sc[j] * qkv[(size_t)j * (3 * DMODEL) + 2 * DMODEL + head * HDIM + d];
    part[g][d] = acc;
    __syncthreads();
    if (tid < HDIM) {
        float o = (part[0][tid] + part[1][tid] + part[2][tid] + part[3][tid]) * invsum;
        out[(size_t)row * DMODEL + head * HDIM + tid] = o;
    }
}

// ---------------------------------------------------------------------------
// SiLU gate: act[i,j] = silu(g[i, 4096+j]) * g[i, j], written in place to
// g[i, j] (so the following GEMM reads lda = MLPD, K = HALF_MLP).
// ---------------------------------------------------------------------------
__global__ void silu_gate_kernel(float* __restrict__ g) {
    int idx = blockIdx.x * blockDim.x + threadIdx.x;
    if (idx >= SEQ * HALF_MLP) return;
    const int i = idx >> 12;          // / 4096
    const int j = idx & (HALF_MLP - 1);
    float* grow = g + (size_t)i * MLPD;
    const float x1 = grow[j];
    const float x2 = grow[j + HALF_MLP];
    const float sil = x2 / (1.0f + __expf(-x2));
    grow[j] = sil * x1;
}

// ---------------------------------------------------------------------------
extern "C" void kernel_launch(void* const* d_in, const int* in_sizes, int n_in,
                              void* d_out, int out_size, void* d_ws, size_t ws_size,
                              hipStream_t stream) {
    const float* x      = (const float*)d_in[0];
    // d_in[1] = mask (causal tril; applied analytically via loop bounds)
    const float* W_attn = (const float*)d_in[2];
    const float* W_out  = (const float*)d_in[3];
    const float* W_ffp  = (const float*)d_in[4];
    const float* W_ffo  = (const float*)d_in[5];
    float* out = (float*)d_out;

    // workspace layout (floats)
    float* ws = (float*)d_ws;
    float* xn   = ws;                              // 2M floats (also reused as hn)
    float* qkv  = xn + (size_t)SEQ * DMODEL;       // 6M floats
    float* attn = qkv + (size_t)SEQ * 3 * DMODEL;  // 2M floats
    float* h    = attn + (size_t)SEQ * DMODEL;     // 2M floats
    float* g    = h + (size_t)SEQ * DMODEL;        // 16M floats
    // total 28M floats = 112 MB

    // 1. xn = LN(x)
    ln_kernel<<<SEQ, 256, 0, stream>>>(x, xn);

    // 2. qkv = xn @ W_attn^T   [2048 x 3072]
    gemm_bt<false><<<dim3(3 * DMODEL / 64, SEQ / 64), 256, 0, stream>>>(
        xn, W_attn, nullptr, qkv, SEQ, 3 * DMODEL, DMODEL, DMODEL, 3 * DMODEL);

    // 3. RoPE in place on q,k
    {
        int total = SEQ * 2 * NHEAD * 32;
        rope_kernel<<<(total + 255) / 256, 256, 0, stream>>>(qkv);
    }

    // 4. attention
    attn_kernel<<<dim3(SEQ, NHEAD), 256, 0, stream>>>(qkv, attn);

    // 5. h = attn @ W_out^T + x
    gemm_bt<true><<<dim3(DMODEL / 64, SEQ / 64), 256, 0, stream>>>(
        attn, W_out, x, h, SEQ, DMODEL, DMODEL, DMODEL, DMODEL);

    // 6. hn = LN(h)   (reuse xn buffer)
    ln_kernel<<<SEQ, 256, 0, stream>>>(h, xn);

    // 7. g = hn @ W_ffp^T   [2048 x 8192]
    gemm_bt<false><<<dim3(MLPD / 64, SEQ / 64), 256, 0, stream>>>(
        xn, W_ffp, nullptr, g, SEQ, MLPD, DMODEL, DMODEL, MLPD);

    // 8. act = silu(x2) * x1, in place into g[:, :4096]
    {
        int total = SEQ * HALF_MLP;
        silu_gate_kernel<<<(total + 255) / 256, 256, 0, stream>>>(g);
    }

    // 9. out = act @ W_ffo^T + h   [2048 x 1024], A stride MLPD, K = 4096
    gemm_bt<true><<<dim3(DMODEL / 64, SEQ / 64), 256, 0, stream>>>(
        g, W_ffo, h, out, SEQ, DMODEL, HALF_MLP, MLPD, DMODEL);
}

// Round 2
// 1887.850 us; speedup vs baseline: 1.7235x; 1.7235x over previous
//
#include <hip/hip_runtime.h>
#include <math.h>

// Problem constants (from reference)
#define DMODEL 1024
#define NHEAD  16
#define HDIM   64
#define SEQ    2048
#define MLPD   8192
#define HALF_MLP 4096
static constexpr float LN_EPS_C = 1e-5f;
#define NEG_BIG (-1e30f)

// ---------------------------------------------------------------------------
// LayerNorm: one block (256 thr) per row of length DMODEL
// ---------------------------------------------------------------------------
__global__ void ln_kernel(const float* __restrict__ in, float* __restrict__ out) {
    const int row = blockIdx.x;
    const int tid = threadIdx.x;
    __shared__ float rs[256], rs2[256];
    const float* r = in + (size_t)row * DMODEL;
    float s = 0.f, s2 = 0.f;
    for (int i = tid; i < DMODEL; i += 256) {
        float v = r[i];
        s += v; s2 += v * v;
    }
    rs[tid] = s; rs2[tid] = s2;
    __syncthreads();
    for (int off = 128; off > 0; off >>= 1) {
        if (tid < off) { rs[tid] += rs[tid + off]; rs2[tid] += rs2[tid + off]; }
        __syncthreads();
    }
    float mu  = rs[0] * (1.0f / DMODEL);
    float var = rs2[0] * (1.0f / DMODEL) - mu * mu;
    float inv = rsqrtf(var + LN_EPS_C);
    for (int i = tid; i < DMODEL; i += 256)
        out[(size_t)row * DMODEL + i] = (r[i] - mu) * inv;
}

// ---------------------------------------------------------------------------
// GEMM: C[M,N] = A[M,K] * B[N,K]^T (+ residual). Tile 64x64, BK=16,
// 256 threads, 4x4 per thread.
// ---------------------------------------------------------------------------
template <bool RES>
__global__ void gemm_bt(const float* __restrict__ A, const float* __restrict__ B,
                        const float* __restrict__ Rsd, float* __restrict__ C,
                        int M, int N, int K, int lda, int ldc) {
    __shared__ float As[16][65];
    __shared__ float Bs[16][65];
    const int n0 = blockIdx.x * 64;
    const int m0 = blockIdx.y * 64;
    const int tid = threadIdx.x;
    const int tx = tid & 15;
    const int ty = tid >> 4;
    const int lr = tid >> 2;
    const int lc = (tid & 3) * 4;

    const float* Aptr = A + (size_t)(m0 + lr) * lda;
    const float* Bptr = B + (size_t)(n0 + lr) * K;

    float acc[4][4] = {};

    for (int k0 = 0; k0 < K; k0 += 16) {
        float4 a = *(const float4*)(Aptr + k0 + lc);
        float4 b = *(const float4*)(Bptr + k0 + lc);
        As[lc + 0][lr] = a.x; As[lc + 1][lr] = a.y;
        As[lc + 2][lr] = a.z; As[lc + 3][lr] = a.w;
        Bs[lc + 0][lr] = b.x; Bs[lc + 1][lr] = b.y;
        Bs[lc + 2][lr] = b.z; Bs[lc + 3][lr] = b.w;
        __syncthreads();
#pragma unroll
        for (int k = 0; k < 16; ++k) {
            float av[4], bv[4];
#pragma unroll
            for (int i = 0; i < 4; ++i) av[i] = As[k][ty * 4 + i];
#pragma unroll
            for (int j = 0; j < 4; ++j) bv[j] = Bs[k][tx * 4 + j];
#pragma unroll
            for (int i = 0; i < 4; ++i)
#pragma unroll
                for (int j = 0; j < 4; ++j)
                    acc[i][j] += av[i] * bv[j];
        }
        __syncthreads();
    }

#pragma unroll
    for (int i = 0; i < 4; ++i) {
        const int m = m0 + ty * 4 + i;
#pragma unroll
        for (int j = 0; j < 4; ++j) {
            const int n = n0 + tx * 4 + j;
            float c = acc[i][j];
            if (RES) c += Rsd[(size_t)m * ldc + n];
            C[(size_t)m * ldc + n] = c;
        }
    }
}

// ---------------------------------------------------------------------------
// RoPE in-place on q and k slices of qkv [SEQ, 3*DMODEL].
// ---------------------------------------------------------------------------
__global__ void rope_kernel(float* __restrict__ qkv) {
    int idx = blockIdx.x * blockDim.x + threadIdx.x;
    if (idx >= SEQ * 2 * NHEAD * 32) return;
    const int p     = idx & 31;
    const int h     = (idx >> 5) & 15;
    const int which = (idx >> 9) & 1;
    const int row   = idx >> 10;
    float* base = qkv + (size_t)row * (3 * DMODEL) + which * DMODEL + h * HDIM;
    const float inv_freq = powf(10000.0f, -(float)p / 32.0f);
    const float ang = (float)row * inv_freq;
    const float c = cosf(ang), s = sinf(ang);
    const float x1 = base[p];
    const float x2 = base[p + 32];
    base[p]      = x1 * c - x2 * s;
    base[p + 32] = x2 * c + x1 * s;
}

// ---------------------------------------------------------------------------
// Flash-style causal attention. One block per (64-row Q tile, head).
// 256 threads; per-thread 4x4 register tiles; online softmax.
// qkv layout: [SEQ, 3*DMODEL]; q at +0, k at +DMODEL, v at +2*DMODEL.
// ---------------------------------------------------------------------------
__global__ void fattn_kernel(const float* __restrict__ qkv, float* __restrict__ out) {
    const int head = blockIdx.y;
    const int m0   = blockIdx.x * 64;
    const int tid  = threadIdx.x;
    const int tx   = tid & 15;     // col group (keys for S, dims for O)
    const int ty   = tid >> 4;     // row group (queries)

    __shared__ float Qt[64][65];   // Qt[d][r]   = Q[r][d] * scale
    __shared__ float Kt[64][65];   // Kt[d][c]   = K[c][d]
    __shared__ float Vs[64][65];   // Vs[k][j]   = V[k][j]
    __shared__ float Ps[64][65];   // Ps[k][r]   = P[r][k]

    const int lr  = tid >> 2;          // 0..63
    const int lc0 = (tid & 3) * 16;    // 0,16,32,48

    // load Q tile (transposed, scaled)
    {
        const float* qrow = qkv + (size_t)(m0 + lr) * (3 * DMODEL) + head * HDIM;
#pragma unroll
        for (int u = 0; u < 4; ++u) {
            float4 v = *(const float4*)(qrow + lc0 + u * 4);
            Qt[lc0 + u * 4 + 0][lr] = v.x * 0.125f;
            Qt[lc0 + u * 4 + 1][lr] = v.y * 0.125f;
            Qt[lc0 + u * 4 + 2][lr] = v.z * 0.125f;
            Qt[lc0 + u * 4 + 3][lr] = v.w * 0.125f;
        }
    }

    float m_i[4], l_i[4], O[4][4];
#pragma unroll
    for (int i = 0; i < 4; ++i) {
        m_i[i] = NEG_BIG; l_i[i] = 0.f;
#pragma unroll
        for (int j = 0; j < 4; ++j) O[i][j] = 0.f;
    }

    for (int j0 = 0; j0 <= m0; j0 += 64) {
        __syncthreads();   // previous iter's Ps/Vs reads complete
        // load K tile (transposed) and V tile (straight)
        {
            const float* krow = qkv + (size_t)(j0 + lr) * (3 * DMODEL) + DMODEL + head * HDIM;
            const float* vrow = qkv + (size_t)(j0 + lr) * (3 * DMODEL) + 2 * DMODEL + head * HDIM;
#pragma unroll
            for (int u = 0; u < 4; ++u) {
                float4 kv = *(const float4*)(krow + lc0 + u * 4);
                Kt[lc0 + u * 4 + 0][lr] = kv.x;
                Kt[lc0 + u * 4 + 1][lr] = kv.y;
                Kt[lc0 + u * 4 + 2][lr] = kv.z;
                Kt[lc0 + u * 4 + 3][lr] = kv.w;
                float4 vv = *(const float4*)(vrow + lc0 + u * 4);
                *(float4*)(&Vs[lr][lc0 + u * 4]) = vv;
            }
        }
        __syncthreads();

        // S = Q K^T (4x4 per thread)
        float S[4][4] = {};
#pragma unroll 8
        for (int d = 0; d < 64; ++d) {
            float av[4], bv[4];
#pragma unroll
            for (int i = 0; i < 4; ++i) av[i] = Qt[d][ty * 4 + i];
#pragma unroll
            for (int j = 0; j < 4; ++j) bv[j] = Kt[d][tx * 4 + j];
#pragma unroll
            for (int i = 0; i < 4; ++i)
#pragma unroll
                for (int j = 0; j < 4; ++j)
                    S[i][j] += av[i] * bv[j];
        }

        // causal mask on diagonal tile
        if (j0 == m0) {
#pragma unroll
            for (int i = 0; i < 4; ++i)
#pragma unroll
                for (int j = 0; j < 4; ++j)
                    if (tx * 4 + j > ty * 4 + i) S[i][j] = NEG_BIG;
        }

        // row max (4 cols local, then across 16 tx lanes)
        float rmax[4];
#pragma unroll
        for (int i = 0; i < 4; ++i)
            rmax[i] = fmaxf(fmaxf(S[i][0], S[i][1]), fmaxf(S[i][2], S[i][3]));
#pragma unroll
        for (int off = 1; off < 16; off <<= 1) {
#pragma unroll
            for (int i = 0; i < 4; ++i)
                rmax[i] = fmaxf(rmax[i], __shfl_xor(rmax[i], off));
        }

        float alpha[4], rsum[4];
#pragma unroll
        for (int i = 0; i < 4; ++i) {
            float mn = fmaxf(m_i[i], rmax[i]);
            alpha[i] = __expf(m_i[i] - mn);
            m_i[i] = mn;
            rsum[i] = 0.f;
        }
        // P = exp(S - m), local row sums
#pragma unroll
        for (int i = 0; i < 4; ++i)
#pragma unroll
            for (int j = 0; j < 4; ++j) {
                float p = __expf(S[i][j] - m_i[i]);
                S[i][j] = p;
                rsum[i] += p;
            }
#pragma unroll
        for (int off = 1; off < 16; off <<= 1) {
#pragma unroll
            for (int i = 0; i < 4; ++i)
                rsum[i] += __shfl_xor(rsum[i], off);
        }
#pragma unroll
        for (int i = 0; i < 4; ++i) {
            l_i[i] = l_i[i] * alpha[i] + rsum[i];
#pragma unroll
            for (int j = 0; j < 4; ++j) O[i][j] *= alpha[i];
        }

        // stash P transposed: Ps[k][r]
#pragma unroll
        for (int i = 0; i < 4; ++i)
#pragma unroll
            for (int j = 0; j < 4; ++j)
                Ps[tx * 4 + j][ty * 4 + i] = S[i][j];
        __syncthreads();

        // O += P V   (4x4 per thread; rows=queries (ty), cols=dims (tx))
#pragma unroll 8
        for (int k = 0; k < 64; ++k) {
            float av[4], bv[4];
#pragma unroll
            for (int i = 0; i < 4; ++i) av[i] = Ps[k][ty * 4 + i];
#pragma unroll
            for (int j = 0; j < 4; ++j) bv[j] = Vs[k][tx * 4 + j];
#pragma unroll
            for (int i = 0; i < 4; ++i)
#pragma unroll
                for (int j = 0; j < 4; ++j)
                    O[i][j] += av[i] * bv[j];
        }
    }

    // epilogue
#pragma unroll
    for (int i = 0; i < 4; ++i) {
        const float inv = 1.0f / l_i[i];
        const int r = m0 + ty * 4 + i;
#pragma unroll
        for (int j = 0; j < 4; ++j)
            out[(size_t)r * DMODEL + head * HDIM + tx * 4 + j] = O[i][j] * inv;
    }
}

// ---------------------------------------------------------------------------
// SiLU gate: g[i,j] = silu(g[i, 4096+j]) * g[i, j] in place.
// ---------------------------------------------------------------------------
__global__ void silu_gate_kernel(float* __restrict__ g) {
    int idx = blockIdx.x * blockDim.x + threadIdx.x;
    if (idx >= SEQ * HALF_MLP) return;
    const int i = idx >> 12;
    const int j = idx & (HALF_MLP - 1);
    float* grow = g + (size_t)i * MLPD;
    const float x1 = grow[j];
    const float x2 = grow[j + HALF_MLP];
    const float sil = x2 / (1.0f + __expf(-x2));
    grow[j] = sil * x1;
}

// ---------------------------------------------------------------------------
extern "C" void kernel_launch(void* const* d_in, const int* in_sizes, int n_in,
                              void* d_out, int out_size, void* d_ws, size_t ws_size,
                              hipStream_t stream) {
    const float* x      = (const float*)d_in[0];
    const float* W_attn = (const float*)d_in[2];
    const float* W_out  = (const float*)d_in[3];
    const float* W_ffp  = (const float*)d_in[4];
    const float* W_ffo  = (const float*)d_in[5];
    float* out = (float*)d_out;

    float* ws = (float*)d_ws;
    float* xn   = ws;
    float* qkv  = xn + (size_t)SEQ * DMODEL;
    float* attn = qkv + (size_t)SEQ * 3 * DMODEL;
    float* h    = attn + (size_t)SEQ * DMODEL;
    float* g    = h + (size_t)SEQ * DMODEL;

    // 1. xn = LN(x)
    ln_kernel<<<SEQ, 256, 0, stream>>>(x, xn);

    // 2. qkv = xn @ W_attn^T
    gemm_bt<false><<<dim3(3 * DMODEL / 64, SEQ / 64), 256, 0, stream>>>(
        xn, W_attn, nullptr, qkv, SEQ, 3 * DMODEL, DMODEL, DMODEL, 3 * DMODEL);

    // 3. RoPE in place on q,k
    {
        int total = SEQ * 2 * NHEAD * 32;
        rope_kernel<<<(total + 255) / 256, 256, 0, stream>>>(qkv);
    }

    // 4. flash attention
    fattn_kernel<<<dim3(SEQ / 64, NHEAD), 256, 0, stream>>>(qkv, attn);

    // 5. h = attn @ W_out^T + x
    gemm_bt<true><<<dim3(DMODEL / 64, SEQ / 64), 256, 0, stream>>>(
        attn, W_out, x, h, SEQ, DMODEL, DMODEL, DMODEL, DMODEL);

    // 6. hn = LN(h)
    ln_kernel<<<SEQ, 256, 0, stream>>>(h, xn);

    // 7. g = hn @ W_ffp^T
    gemm_bt<false><<<dim3(MLPD / 64, SEQ / 64), 256, 0, stream>>>(
        xn, W_ffp, nullptr, g, SEQ, MLPD, DMODEL, DMODEL, MLPD);

    // 8. silu gate in place
    {
        int total = SEQ * HALF_MLP;
        silu_gate_kernel<<<(total + 255) / 256, 256, 0, stream>>>(g);
    }

    // 9. out = act @ W_ffo^T + h
    gemm_bt<true><<<dim3(DMODEL / 64, SEQ / 64), 256, 0, stream>>>(
        g, W_ffo, h, out, SEQ, DMODEL, HALF_MLP, MLPD, DMODEL);
}

// Round 3
// 733.756 us; speedup vs baseline: 4.4342x; 2.5729x over previous
//
#include <hip/hip_runtime.h>
#include <math.h>

// Problem constants (from reference)
#define DMODEL 1024
#define NHEAD  16
#define HDIM   64
#define SEQ    2048
#define MLPD   8192
#define HALF_MLP 4096
static constexpr float LN_EPS_C = 1e-5f;
#define NEG_BIG (-1e30f)

typedef short bf16x8 __attribute__((ext_vector_type(8)));
typedef float f32x4  __attribute__((ext_vector_type(4)));

__device__ __forceinline__ unsigned short f2b(float f) {
    unsigned int u = __float_as_uint(f);
    u = (u + 0x7FFFu + ((u >> 16) & 1u)) >> 16;   // RNE
    return (unsigned short)u;
}
__device__ __forceinline__ float b2f(unsigned short h) {
    return __uint_as_float((unsigned int)h << 16);
}

__device__ __forceinline__ void async_copy16(const unsigned short* g, unsigned short* l) {
    __builtin_amdgcn_global_load_lds(
        (const __attribute__((address_space(1))) unsigned int*)(g),
        (__attribute__((address_space(3))) unsigned int*)(l),
        16, 0, 0);
}

// ---------------------------------------------------------------------------
// fp32 -> bf16 pack (weights), 4 elements/thread
// ---------------------------------------------------------------------------
__global__ void f2b_kernel(const float* __restrict__ in, unsigned short* __restrict__ out, int n) {
    int i = (blockIdx.x * blockDim.x + threadIdx.x) * 4;
    if (i >= n) return;
    float4 v = *(const float4*)(in + i);
    ushort4 o;
    o.x = f2b(v.x); o.y = f2b(v.y); o.z = f2b(v.z); o.w = f2b(v.w);
    *(ushort4*)(out + i) = o;
}

// ---------------------------------------------------------------------------
// LayerNorm -> bf16 out. One block (256 thr) per row.
// ---------------------------------------------------------------------------
__global__ void ln_kernel(const float* __restrict__ in, unsigned short* __restrict__ out) {
    const int row = blockIdx.x;
    const int tid = threadIdx.x;
    __shared__ float rs[256], rs2[256];
    const float* r = in + (size_t)row * DMODEL;
    float s = 0.f, s2 = 0.f;
    for (int i = tid; i < DMODEL; i += 256) {
        float v = r[i];
        s += v; s2 += v * v;
    }
    rs[tid] = s; rs2[tid] = s2;
    __syncthreads();
    for (int off = 128; off > 0; off >>= 1) {
        if (tid < off) { rs[tid] += rs[tid + off]; rs2[tid] += rs2[tid + off]; }
        __syncthreads();
    }
    float mu  = rs[0] * (1.0f / DMODEL);
    float var = rs2[0] * (1.0f / DMODEL) - mu * mu;
    float inv = rsqrtf(var + LN_EPS_C);
    for (int i = tid; i < DMODEL; i += 256)
        out[(size_t)row * DMODEL + i] = f2b((r[i] - mu) * inv);
}

// ---------------------------------------------------------------------------
// bf16 MFMA GEMM (m97 structure): C[M,N] = A[M,K] * B[N,K]^T (+ fp32 residual)
// A packed bf16 stride lda, B packed bf16 stride K (weights), C stride ldc.
// 128x128 tile / block, 256 thr = 4 waves (2x2), each wave 64x64 via 4x4
// grid of 16x16x32 MFMAs. BK=32. global_load_lds width=16 staging.
// ---------------------------------------------------------------------------
template <bool RES, bool OBF>
__global__ __launch_bounds__(256)
void gemm_mfma(const unsigned short* __restrict__ A, const unsigned short* __restrict__ B,
               const float* __restrict__ Rsd, void* __restrict__ Cv,
               int K, int lda, int ldc) {
    __shared__ unsigned short As[128 * 32];
    __shared__ unsigned short Bs[128 * 32];
    const int tid  = threadIdx.x;
    const int lane = tid & 63;
    const int w    = tid >> 6;      // wave 0..3
    const int wm   = w >> 1;        // wave row (0,1)
    const int wn   = w & 1;         // wave col (0,1)
    const int m0   = blockIdx.y * 128;
    const int n0   = blockIdx.x * 128;

    f32x4 acc[4][4] = {};

    // staging: wave w covers tile rows [w*32, w*32+32), two 16-row calls.
    // lane l -> row +(l>>2), 16B chunk (l&3) within the 64B row.
    const int srow = lane >> 2;
    const int scol = (lane & 3) * 8;
    const unsigned short* Abase = A + (size_t)(m0 + w * 32 + srow) * lda + scol;
    const unsigned short* Bbase = B + (size_t)(n0 + w * 32 + srow) * K + scol;
    unsigned short* AsW = &As[(w * 32) * 32];
    unsigned short* BsW = &Bs[(w * 32) * 32];

    // fragment read coords
    const int fr = lane & 15;
    const int fk = (lane >> 4) * 8;

    for (int k0 = 0; k0 < K; k0 += 32) {
        async_copy16(Abase + k0,            AsW);
        async_copy16(Abase + k0 + 16 * lda, AsW + 16 * 32);
        async_copy16(Bbase + k0,            BsW);
        async_copy16(Bbase + k0 + 16 * (size_t)K, BsW + 16 * 32);
        __syncthreads();

        bf16x8 af[4], bfr[4];
#pragma unroll
        for (int i = 0; i < 4; ++i)
            af[i] = *(const bf16x8*)(&As[(wm * 64 + i * 16 + fr) * 32 + fk]);
#pragma unroll
        for (int j = 0; j < 4; ++j)
            bfr[j] = *(const bf16x8*)(&Bs[(wn * 64 + j * 16 + fr) * 32 + fk]);
#pragma unroll
        for (int i = 0; i < 4; ++i)
#pragma unroll
            for (int j = 0; j < 4; ++j)
                acc[i][j] = __builtin_amdgcn_mfma_f32_16x16x32_bf16(af[i], bfr[j], acc[i][j], 0, 0, 0);
        __syncthreads();
    }

    // epilogue: C/D layout col=lane&15, row=(lane>>4)*4+reg  [verified m89/m91]
    const int erow = (lane >> 4) * 4;
    const int ecol = lane & 15;
#pragma unroll
    for (int i = 0; i < 4; ++i)
#pragma unroll
        for (int j = 0; j < 4; ++j) {
            const int colg = n0 + wn * 64 + j * 16 + ecol;
#pragma unroll
            for (int r = 0; r < 4; ++r) {
                const int rowg = m0 + wm * 64 + i * 16 + erow + r;
                float v = acc[i][j][r];
                if (RES) v += Rsd[(size_t)rowg * ldc + colg];
                if (OBF) ((unsigned short*)Cv)[(size_t)rowg * ldc + colg] = f2b(v);
                else     ((float*)Cv)[(size_t)rowg * ldc + colg] = v;
            }
        }
}

// ---------------------------------------------------------------------------
// RoPE in-place on q and k slices of qkv [SEQ, 3*DMODEL] (fp32).
// ---------------------------------------------------------------------------
__global__ void rope_kernel(float* __restrict__ qkv) {
    int idx = blockIdx.x * blockDim.x + threadIdx.x;
    if (idx >= SEQ * 2 * NHEAD * 32) return;
    const int p     = idx & 31;
    const int h     = (idx >> 5) & 15;
    const int which = (idx >> 9) & 1;
    const int row   = idx >> 10;
    float* base = qkv + (size_t)row * (3 * DMODEL) + which * DMODEL + h * HDIM;
    const float inv_freq = powf(10000.0f, -(float)p / 32.0f);
    const float ang = (float)row * inv_freq;
    const float c = cosf(ang), s = sinf(ang);
    const float x1 = base[p];
    const float x2 = base[p + 32];
    base[p]      = x1 * c - x2 * s;
    base[p + 32] = x2 * c + x1 * s;
}

// ---------------------------------------------------------------------------
// Flash-style causal attention (fp32 compute), bf16 output.
// One block per (64-row Q tile, head). 256 thr; 4x4 reg tiles; online softmax.
// ---------------------------------------------------------------------------
__global__ void fattn_kernel(const float* __restrict__ qkv, unsigned short* __restrict__ out) {
    const int head = blockIdx.y;
    const int m0   = blockIdx.x * 64;
    const int tid  = threadIdx.x;
    const int tx   = tid & 15;
    const int ty   = tid >> 4;

    __shared__ float Qt[64][65];
    __shared__ float Kt[64][65];
    __shared__ float Vs[64][65];
    __shared__ float Ps[64][65];

    const int lr  = tid >> 2;
    const int lc0 = (tid & 3) * 16;

    {
        const float* qrow = qkv + (size_t)(m0 + lr) * (3 * DMODEL) + head * HDIM;
#pragma unroll
        for (int u = 0; u < 4; ++u) {
            float4 v = *(const float4*)(qrow + lc0 + u * 4);
            Qt[lc0 + u * 4 + 0][lr] = v.x * 0.125f;
            Qt[lc0 + u * 4 + 1][lr] = v.y * 0.125f;
            Qt[lc0 + u * 4 + 2][lr] = v.z * 0.125f;
            Qt[lc0 + u * 4 + 3][lr] = v.w * 0.125f;
        }
    }

    float m_i[4], l_i[4], O[4][4];
#pragma unroll
    for (int i = 0; i < 4; ++i) {
        m_i[i] = NEG_BIG; l_i[i] = 0.f;
#pragma unroll
        for (int j = 0; j < 4; ++j) O[i][j] = 0.f;
    }

    for (int j0 = 0; j0 <= m0; j0 += 64) {
        __syncthreads();
        {
            const float* krow = qkv + (size_t)(j0 + lr) * (3 * DMODEL) + DMODEL + head * HDIM;
            const float* vrow = qkv + (size_t)(j0 + lr) * (3 * DMODEL) + 2 * DMODEL + head * HDIM;
#pragma unroll
            for (int u = 0; u < 4; ++u) {
                float4 kv = *(const float4*)(krow + lc0 + u * 4);
                Kt[lc0 + u * 4 + 0][lr] = kv.x;
                Kt[lc0 + u * 4 + 1][lr] = kv.y;
                Kt[lc0 + u * 4 + 2][lr] = kv.z;
                Kt[lc0 + u * 4 + 3][lr] = kv.w;
                float4 vv = *(const float4*)(vrow + lc0 + u * 4);
                *(float4*)(&Vs[lr][lc0 + u * 4]) = vv;
            }
        }
        __syncthreads();

        float S[4][4] = {};
#pragma unroll 8
        for (int d = 0; d < 64; ++d) {
            float av[4], bv[4];
#pragma unroll
            for (int i = 0; i < 4; ++i) av[i] = Qt[d][ty * 4 + i];
#pragma unroll
            for (int j = 0; j < 4; ++j) bv[j] = Kt[d][tx * 4 + j];
#pragma unroll
            for (int i = 0; i < 4; ++i)
#pragma unroll
                for (int j = 0; j < 4; ++j)
                    S[i][j] += av[i] * bv[j];
        }

        if (j0 == m0) {
#pragma unroll
            for (int i = 0; i < 4; ++i)
#pragma unroll
                for (int j = 0; j < 4; ++j)
                    if (tx * 4 + j > ty * 4 + i) S[i][j] = NEG_BIG;
        }

        float rmax[4];
#pragma unroll
        for (int i = 0; i < 4; ++i)
            rmax[i] = fmaxf(fmaxf(S[i][0], S[i][1]), fmaxf(S[i][2], S[i][3]));
#pragma unroll
        for (int off = 1; off < 16; off <<= 1) {
#pragma unroll
            for (int i = 0; i < 4; ++i)
                rmax[i] = fmaxf(rmax[i], __shfl_xor(rmax[i], off));
        }

        float alpha[4], rsum[4];
#pragma unroll
        for (int i = 0; i < 4; ++i) {
            float mn = fmaxf(m_i[i], rmax[i]);
            alpha[i] = __expf(m_i[i] - mn);
            m_i[i] = mn;
            rsum[i] = 0.f;
        }
#pragma unroll
        for (int i = 0; i < 4; ++i)
#pragma unroll
            for (int j = 0; j < 4; ++j) {
                float p = __expf(S[i][j] - m_i[i]);
                S[i][j] = p;
                rsum[i] += p;
            }
#pragma unroll
        for (int off = 1; off < 16; off <<= 1) {
#pragma unroll
            for (int i = 0; i < 4; ++i)
                rsum[i] += __shfl_xor(rsum[i], off);
        }
#pragma unroll
        for (int i = 0; i < 4; ++i) {
            l_i[i] = l_i[i] * alpha[i] + rsum[i];
#pragma unroll
            for (int j = 0; j < 4; ++j) O[i][j] *= alpha[i];
        }

#pragma unroll
        for (int i = 0; i < 4; ++i)
#pragma unroll
            for (int j = 0; j < 4; ++j)
                Ps[tx * 4 + j][ty * 4 + i] = S[i][j];
        __syncthreads();

#pragma unroll 8
        for (int k = 0; k < 64; ++k) {
            float av[4], bv[4];
#pragma unroll
            for (int i = 0; i < 4; ++i) av[i] = Ps[k][ty * 4 + i];
#pragma unroll
            for (int j = 0; j < 4; ++j) bv[j] = Vs[k][tx * 4 + j];
#pragma unroll
            for (int i = 0; i < 4; ++i)
#pragma unroll
                for (int j = 0; j < 4; ++j)
                    O[i][j] += av[i] * bv[j];
        }
    }

#pragma unroll
    for (int i = 0; i < 4; ++i) {
        const float inv = 1.0f / l_i[i];
        const int r = m0 + ty * 4 + i;
#pragma unroll
        for (int j = 0; j < 4; ++j)
            out[(size_t)r * DMODEL + head * HDIM + tx * 4 + j] = f2b(O[i][j] * inv);
    }
}

// ---------------------------------------------------------------------------
// SiLU gate on bf16 g [SEQ][MLPD]: g[i,j] = silu(g[i,4096+j]) * g[i,j], j<4096.
// 4 elements/thread.
// ---------------------------------------------------------------------------
__global__ void silu_bf16_kernel(unsigned short* __restrict__ g) {
    int idx = blockIdx.x * blockDim.x + threadIdx.x;
    if (idx >= SEQ * HALF_MLP / 4) return;
    const int i = idx >> 10;             // / (4096/4)
    const int j = (idx & 1023) * 4;
    unsigned short* row = g + (size_t)i * MLPD;
    ushort4 a = *(const ushort4*)(row + j);
    ushort4 b = *(const ushort4*)(row + j + HALF_MLP);
    float x1[4] = { b2f(a.x), b2f(a.y), b2f(a.z), b2f(a.w) };
    float x2[4] = { b2f(b.x), b2f(b.y), b2f(b.z), b2f(b.w) };
    ushort4 o;
    unsigned short* op = (unsigned short*)&o;
#pragma unroll
    for (int t = 0; t < 4; ++t) {
        float sil = x2[t] / (1.0f + __expf(-x2[t]));
        op[t] = f2b(sil * x1[t]);
    }
    *(ushort4*)(row + j) = o;
}

// ---------------------------------------------------------------------------
extern "C" void kernel_launch(void* const* d_in, const int* in_sizes, int n_in,
                              void* d_out, int out_size, void* d_ws, size_t ws_size,
                              hipStream_t stream) {
    const float* x      = (const float*)d_in[0];
    const float* W_attn = (const float*)d_in[2];
    const float* W_out  = (const float*)d_in[3];
    const float* W_ffp  = (const float*)d_in[4];
    const float* W_ffo  = (const float*)d_in[5];
    float* out = (float*)d_out;

    // workspace layout (104 MB total)
    char* wsb = (char*)d_ws;
    float*          qkv     = (float*)(wsb);                          // 24 MB fp32 [2048][3072]
    float*          h       = (float*)(wsb + (24u << 20));            //  8 MB fp32 [2048][1024]
    unsigned short* g       = (unsigned short*)(wsb + (32u << 20));   // 32 MB bf16 [2048][8192]
    unsigned short* xnb     = (unsigned short*)(wsb + (64u << 20));   //  4 MB bf16 [2048][1024]
    unsigned short* attnb   = (unsigned short*)(wsb + (68u << 20));   //  4 MB bf16 [2048][1024]
    unsigned short* wb_attn = (unsigned short*)(wsb + (72u << 20));   //  6 MB bf16 [3072][1024]
    unsigned short* wb_out  = (unsigned short*)(wsb + (78u << 20));   //  2 MB bf16 [1024][1024]
    unsigned short* wb_ffp  = (unsigned short*)(wsb + (80u << 20));   // 16 MB bf16 [8192][1024]
    unsigned short* wb_ffo  = (unsigned short*)(wsb + (96u << 20));   //  8 MB bf16 [1024][4096]

    // 0. weight conversions fp32 -> bf16
    {
        int n1 = 3 * DMODEL * DMODEL, n2 = DMODEL * DMODEL,
            n3 = MLPD * DMODEL, n4 = DMODEL * HALF_MLP;
        f2b_kernel<<<(n1 / 4 + 255) / 256, 256, 0, stream>>>(W_attn, wb_attn, n1);
        f2b_kernel<<<(n2 / 4 + 255) / 256, 256, 0, stream>>>(W_out,  wb_out,  n2);
        f2b_kernel<<<(n3 / 4 + 255) / 256, 256, 0, stream>>>(W_ffp,  wb_ffp,  n3);
        f2b_kernel<<<(n4 / 4 + 255) / 256, 256, 0, stream>>>(W_ffo,  wb_ffo,  n4);
    }

    // 1. xn = LN(x) -> bf16
    ln_kernel<<<SEQ, 256, 0, stream>>>(x, xnb);

    // 2. qkv = xn @ W_attn^T  (fp32 out)
    gemm_mfma<false, false><<<dim3(3 * DMODEL / 128, SEQ / 128), 256, 0, stream>>>(
        xnb, wb_attn, nullptr, qkv, DMODEL, DMODEL, 3 * DMODEL);

    // 3. RoPE in place on q,k
    {
        int total = SEQ * 2 * NHEAD * 32;
        rope_kernel<<<(total + 255) / 256, 256, 0, stream>>>(qkv);
    }

    // 4. flash attention -> bf16
    fattn_kernel<<<dim3(SEQ / 64, NHEAD), 256, 0, stream>>>(qkv, attnb);

    // 5. h = attn @ W_out^T + x  (fp32 out)
    gemm_mfma<true, false><<<dim3(DMODEL / 128, SEQ / 128), 256, 0, stream>>>(
        attnb, wb_out, x, h, DMODEL, DMODEL, DMODEL);

    // 6. hn = LN(h) -> bf16
    ln_kernel<<<SEQ, 256, 0, stream>>>(h, xnb);

    // 7. g = hn @ W_ffp^T  (bf16 out)
    gemm_mfma<false, true><<<dim3(MLPD / 128, SEQ / 128), 256, 0, stream>>>(
        xnb, wb_ffp, nullptr, g, DMODEL, DMODEL, MLPD);

    // 8. silu gate in place (bf16)
    silu_bf16_kernel<<<(SEQ * HALF_MLP / 4 + 255) / 256, 256, 0, stream>>>(g);

    // 9. out = act @ W_ffo^T + h  (fp32 out), A stride MLPD, K = 4096
    gemm_mfma<true, false><<<dim3(DMODEL / 128, SEQ / 128), 256, 0, stream>>>(
        g, wb_ffo, h, out, HALF_MLP, MLPD, DMODEL);
}

// Round 4
// 446.082 us; speedup vs baseline: 7.2938x; 1.6449x over previous
//
#include <hip/hip_runtime.h>
#include <math.h>

// Problem constants (from reference)
#define DMODEL 1024
#define NHEAD  16
#define HDIM   64
#define SEQ    2048
#define MLPD   8192
#define HALF_MLP 4096
static constexpr float LN_EPS_C = 1e-5f;
#define NEG_BIG (-1e30f)

typedef short bf16x8 __attribute__((ext_vector_type(8)));
typedef float f32x4  __attribute__((ext_vector_type(4)));

__device__ __forceinline__ unsigned short f2b(float f) {
    unsigned int u = __float_as_uint(f);
    u = (u + 0x7FFFu + ((u >> 16) & 1u)) >> 16;   // RNE
    return (unsigned short)u;
}
__device__ __forceinline__ float b2f(unsigned short h) {
    return __uint_as_float((unsigned int)h << 16);
}

__device__ __forceinline__ void async_copy16(const unsigned short* g, unsigned short* l) {
    __builtin_amdgcn_global_load_lds(
        (const __attribute__((address_space(1))) unsigned int*)(g),
        (__attribute__((address_space(3))) unsigned int*)(l),
        16, 0, 0);
}

// ---------------------------------------------------------------------------
// fp32 -> bf16 pack (weights), 4 elements/thread
// ---------------------------------------------------------------------------
__global__ void f2b_kernel(const float* __restrict__ in, unsigned short* __restrict__ out, int n) {
    int i = (blockIdx.x * blockDim.x + threadIdx.x) * 4;
    if (i >= n) return;
    float4 v = *(const float4*)(in + i);
    ushort4 o;
    o.x = f2b(v.x); o.y = f2b(v.y); o.z = f2b(v.z); o.w = f2b(v.w);
    *(ushort4*)(out + i) = o;
}

// ---------------------------------------------------------------------------
// LayerNorm -> bf16 out. One block (256 thr) per row.
// ---------------------------------------------------------------------------
__global__ void ln_kernel(const float* __restrict__ in, unsigned short* __restrict__ out) {
    const int row = blockIdx.x;
    const int tid = threadIdx.x;
    __shared__ float rs[256], rs2[256];
    const float* r = in + (size_t)row * DMODEL;
    float s = 0.f, s2 = 0.f;
    for (int i = tid; i < DMODEL; i += 256) {
        float v = r[i];
        s += v; s2 += v * v;
    }
    rs[tid] = s; rs2[tid] = s2;
    __syncthreads();
    for (int off = 128; off > 0; off >>= 1) {
        if (tid < off) { rs[tid] += rs[tid + off]; rs2[tid] += rs2[tid + off]; }
        __syncthreads();
    }
    float mu  = rs[0] * (1.0f / DMODEL);
    float var = rs2[0] * (1.0f / DMODEL) - mu * mu;
    float inv = rsqrtf(var + LN_EPS_C);
    for (int i = tid; i < DMODEL; i += 256)
        out[(size_t)row * DMODEL + i] = f2b((r[i] - mu) * inv);
}

// ---------------------------------------------------------------------------
// bf16 MFMA GEMM (m97 structure): C[M,N] = A[M,K] * B[N,K]^T (+ fp32 residual)
// 128x128 tile / block, 256 thr = 4 waves (2x2), each wave 64x64 via 4x4
// grid of 16x16x32 MFMAs. BK=32. global_load_lds width=16 staging.
// ---------------------------------------------------------------------------
template <bool RES, bool OBF>
__global__ __launch_bounds__(256)
void gemm_mfma(const unsigned short* __restrict__ A, const unsigned short* __restrict__ B,
               const float* __restrict__ Rsd, void* __restrict__ Cv,
               int K, int lda, int ldc) {
    __shared__ unsigned short As[128 * 32];
    __shared__ unsigned short Bs[128 * 32];
    const int tid  = threadIdx.x;
    const int lane = tid & 63;
    const int w    = tid >> 6;
    const int wm   = w >> 1;
    const int wn   = w & 1;
    const int m0   = blockIdx.y * 128;
    const int n0   = blockIdx.x * 128;

    f32x4 acc[4][4] = {};

    const int srow = lane >> 2;
    const int scol = (lane & 3) * 8;
    const unsigned short* Abase = A + (size_t)(m0 + w * 32 + srow) * lda + scol;
    const unsigned short* Bbase = B + (size_t)(n0 + w * 32 + srow) * K + scol;
    unsigned short* AsW = &As[(w * 32) * 32];
    unsigned short* BsW = &Bs[(w * 32) * 32];

    const int fr = lane & 15;
    const int fk = (lane >> 4) * 8;

    for (int k0 = 0; k0 < K; k0 += 32) {
        async_copy16(Abase + k0,            AsW);
        async_copy16(Abase + k0 + 16 * lda, AsW + 16 * 32);
        async_copy16(Bbase + k0,            BsW);
        async_copy16(Bbase + k0 + 16 * (size_t)K, BsW + 16 * 32);
        __syncthreads();

        bf16x8 af[4], bfr[4];
#pragma unroll
        for (int i = 0; i < 4; ++i)
            af[i] = *(const bf16x8*)(&As[(wm * 64 + i * 16 + fr) * 32 + fk]);
#pragma unroll
        for (int j = 0; j < 4; ++j)
            bfr[j] = *(const bf16x8*)(&Bs[(wn * 64 + j * 16 + fr) * 32 + fk]);
#pragma unroll
        for (int i = 0; i < 4; ++i)
#pragma unroll
            for (int j = 0; j < 4; ++j)
                acc[i][j] = __builtin_amdgcn_mfma_f32_16x16x32_bf16(af[i], bfr[j], acc[i][j], 0, 0, 0);
        __syncthreads();
    }

    const int erow = (lane >> 4) * 4;
    const int ecol = lane & 15;
#pragma unroll
    for (int i = 0; i < 4; ++i)
#pragma unroll
        for (int j = 0; j < 4; ++j) {
            const int colg = n0 + wn * 64 + j * 16 + ecol;
#pragma unroll
            for (int r = 0; r < 4; ++r) {
                const int rowg = m0 + wm * 64 + i * 16 + erow + r;
                float v = acc[i][j][r];
                if (RES) v += Rsd[(size_t)rowg * ldc + colg];
                if (OBF) ((unsigned short*)Cv)[(size_t)rowg * ldc + colg] = f2b(v);
                else     ((float*)Cv)[(size_t)rowg * ldc + colg] = v;
            }
        }
}

// ---------------------------------------------------------------------------
// QKV pack: rope+scale q,k -> bf16 Qp/Kp [H][S][64]; transpose v -> Vt [H][64][S].
// One block per (64-row chunk, head). 256 threads.
// ---------------------------------------------------------------------------
__global__ void qkv_pack(const float* __restrict__ qkv,
                         unsigned short* __restrict__ Qp,
                         unsigned short* __restrict__ Kp,
                         unsigned short* __restrict__ Vt) {
    const int head = blockIdx.y;
    const int m0   = blockIdx.x * 64;
    const int tid  = threadIdx.x;
    const int r    = tid >> 2;         // 0..63 (row for q/k; dim for Vt write)
    const int c    = (tid & 3) * 16;   // 0,16,32,48

    __shared__ float Vl[64][65];

    const float* base = qkv + (size_t)(m0 + r) * (3 * DMODEL) + head * HDIM;

    // stage V tile into LDS (straight)
#pragma unroll
    for (int u = 0; u < 4; ++u) {
        float4 v = *(const float4*)(base + 2 * DMODEL + c + u * 4);
        Vl[r][c + u * 4 + 0] = v.x; Vl[r][c + u * 4 + 1] = v.y;
        Vl[r][c + u * 4 + 2] = v.z; Vl[r][c + u * 4 + 3] = v.w;
    }

    // rope q and k: out[d] = x[d]*cos(p) + (d<32 ? -1 : +1)*x[d^32]*sin(p), p=d&31
    const float pos = (float)(m0 + r);
    unsigned short qo[16], ko[16];
#pragma unroll
    for (int u = 0; u < 16; ++u) {
        const int d = c + u;
        const int p = d & 31;
        const float inv_freq = powf(10000.0f, -(float)p / 32.0f);
        const float ang = pos * inv_freq;
        const float cs = cosf(ang), sn = sinf(ang);
        const float sgn = (d < 32) ? -1.0f : 1.0f;
        float q1 = base[d], q2 = base[d ^ 32];
        float k1 = base[DMODEL + d], k2 = base[DMODEL + (d ^ 32)];
        qo[u] = f2b((q1 * cs + sgn * q2 * sn) * 0.125f);
        ko[u] = f2b(k1 * cs + sgn * k2 * sn);
    }
    {
        unsigned short* qdst = Qp + ((size_t)head * SEQ + m0 + r) * HDIM + c;
        unsigned short* kdst = Kp + ((size_t)head * SEQ + m0 + r) * HDIM + c;
#pragma unroll
        for (int u = 0; u < 2; ++u) {
            *(bf16x8*)(qdst + u * 8) = *(bf16x8*)(&qo[u * 8]);
            *(bf16x8*)(kdst + u * 8) = *(bf16x8*)(&ko[u * 8]);
        }
    }

    __syncthreads();

    // transposed V write: Vt[head][d=r][m0+c..c+16] = Vl[key][d]
    unsigned short vo[16];
#pragma unroll
    for (int u = 0; u < 16; ++u) vo[u] = f2b(Vl[c + u][r]);
    unsigned short* vdst = Vt + ((size_t)head * HDIM + r) * SEQ + m0 + c;
#pragma unroll
    for (int u = 0; u < 2; ++u)
        *(bf16x8*)(vdst + u * 8) = *(bf16x8*)(&vo[u * 8]);
}

// ---------------------------------------------------------------------------
// MFMA flash attention. One block per (64-row Q tile, head); 4 waves, each
// owning a 16-row query strip. bf16 Q/K/V, fp32 online softmax.
// ---------------------------------------------------------------------------
#define LDQ 72   // padded row stride (shorts): 144 B -> 2-way (free) banks
__global__ __launch_bounds__(256)
void fattn_mfma(const unsigned short* __restrict__ Qp,
                const unsigned short* __restrict__ Kp,
                const unsigned short* __restrict__ Vt,
                unsigned short* __restrict__ out) {
    const int head = blockIdx.y;
    const int bx   = blockIdx.x;
    const int mt   = (bx & 1) ? (31 - (bx >> 1)) : (bx >> 1);  // zig-zag balance
    const int m0   = mt * 64;
    const int tid  = threadIdx.x;
    const int lane = tid & 63;
    const int w    = tid >> 6;
    const int fr   = lane & 15;
    const int quad = lane >> 4;

    __shared__ unsigned short Qs[64 * LDQ];
    __shared__ unsigned short Ks[64 * LDQ];
    __shared__ unsigned short Vs[64 * LDQ];
    __shared__ unsigned short Ps[64 * LDQ];

    const unsigned short* Qg = Qp + ((size_t)head * SEQ + m0) * HDIM;
    const unsigned short* Kg = Kp + (size_t)head * SEQ * HDIM;
    const unsigned short* Vg = Vt + (size_t)head * HDIM * SEQ;

    const int sr = tid >> 2;          // staging row 0..63
    const int sc = (tid & 3) * 16;    // staging col (shorts)

    // stage Q once
    {
        bf16x8 a = *(const bf16x8*)(Qg + sr * HDIM + sc);
        bf16x8 b = *(const bf16x8*)(Qg + sr * HDIM + sc + 8);
        *(bf16x8*)(&Qs[sr * LDQ + sc]) = a;
        *(bf16x8*)(&Qs[sr * LDQ + sc + 8]) = b;
    }

    f32x4 accO[4] = {};
    float m_i[4], l_i[4];
#pragma unroll
    for (int r = 0; r < 4; ++r) { m_i[r] = NEG_BIG; l_i[r] = 0.f; }

    for (int j0 = 0; j0 <= m0; j0 += 64) {
        __syncthreads();   // prev iter reads of Ks/Vs done (also covers Q staging)
        {
            bf16x8 k1 = *(const bf16x8*)(Kg + (size_t)(j0 + sr) * HDIM + sc);
            bf16x8 k2 = *(const bf16x8*)(Kg + (size_t)(j0 + sr) * HDIM + sc + 8);
            bf16x8 v1 = *(const bf16x8*)(Vg + (size_t)sr * SEQ + j0 + sc);
            bf16x8 v2 = *(const bf16x8*)(Vg + (size_t)sr * SEQ + j0 + sc + 8);
            *(bf16x8*)(&Ks[sr * LDQ + sc]) = k1;
            *(bf16x8*)(&Ks[sr * LDQ + sc + 8]) = k2;
            *(bf16x8*)(&Vs[sr * LDQ + sc]) = v1;
            *(bf16x8*)(&Vs[sr * LDQ + sc + 8]) = v2;
        }
        __syncthreads();

        // S = Q K^T : wave strip 16 q-rows x 64 keys
        f32x4 accS[4] = {};
#pragma unroll
        for (int kk = 0; kk < 64; kk += 32) {
            bf16x8 af = *(const bf16x8*)(&Qs[(w * 16 + fr) * LDQ + kk + quad * 8]);
#pragma unroll
            for (int j = 0; j < 4; ++j) {
                bf16x8 bf_ = *(const bf16x8*)(&Ks[(j * 16 + fr) * LDQ + kk + quad * 8]);
                accS[j] = __builtin_amdgcn_mfma_f32_16x16x32_bf16(af, bf_, accS[j], 0, 0, 0);
            }
        }

        // causal mask (diagonal tile only). C layout: col=fr, row=quad*4+r
        if (j0 == m0) {
#pragma unroll
            for (int j = 0; j < 4; ++j)
#pragma unroll
                for (int r = 0; r < 4; ++r)
                    if (j * 16 + fr > w * 16 + quad * 4 + r) accS[j][r] = NEG_BIG;
        }

        // row max across 4 j-tiles then 16 lanes
        float rmax[4];
#pragma unroll
        for (int r = 0; r < 4; ++r)
            rmax[r] = fmaxf(fmaxf(accS[0][r], accS[1][r]), fmaxf(accS[2][r], accS[3][r]));
#pragma unroll
        for (int off = 1; off < 16; off <<= 1)
#pragma unroll
            for (int r = 0; r < 4; ++r)
                rmax[r] = fmaxf(rmax[r], __shfl_xor(rmax[r], off));

        float alpha[4], rsum[4];
#pragma unroll
        for (int r = 0; r < 4; ++r) {
            float mn = fmaxf(m_i[r], rmax[r]);
            alpha[r] = __expf(m_i[r] - mn);
            m_i[r] = mn;
            rsum[r] = 0.f;
        }
#pragma unroll
        for (int j = 0; j < 4; ++j)
#pragma unroll
            for (int r = 0; r < 4; ++r) {
                float p = __expf(accS[j][r] - m_i[r]);
                accS[j][r] = p;
                rsum[r] += p;
            }
#pragma unroll
        for (int off = 1; off < 16; off <<= 1)
#pragma unroll
            for (int r = 0; r < 4; ++r)
                rsum[r] += __shfl_xor(rsum[r], off);
#pragma unroll
        for (int r = 0; r < 4; ++r) {
            l_i[r] = l_i[r] * alpha[r] + rsum[r];
#pragma unroll
            for (int j = 0; j < 4; ++j) accO[j][r] *= alpha[r];
        }

        // P -> LDS (wave-private rows w*16..w*16+15), bf16, A-operand layout
#pragma unroll
        for (int j = 0; j < 4; ++j)
#pragma unroll
            for (int r = 0; r < 4; ++r)
                Ps[(w * 16 + quad * 4 + r) * LDQ + j * 16 + fr] = f2b(accS[j][r]);

        // O += P V
#pragma unroll
        for (int kk = 0; kk < 64; kk += 32) {
            bf16x8 af = *(const bf16x8*)(&Ps[(w * 16 + fr) * LDQ + kk + quad * 8]);
#pragma unroll
            for (int j = 0; j < 4; ++j) {
                bf16x8 bf_ = *(const bf16x8*)(&Vs[(j * 16 + fr) * LDQ + kk + quad * 8]);
                accO[j] = __builtin_amdgcn_mfma_f32_16x16x32_bf16(af, bf_, accO[j], 0, 0, 0);
            }
        }
    }

    // epilogue: O row=quad*4+r (query), col=fr (dim within j-tile)
#pragma unroll
    for (int r = 0; r < 4; ++r) {
        const float inv = 1.0f / l_i[r];
        const int qrow = m0 + w * 16 + quad * 4 + r;
#pragma unroll
        for (int j = 0; j < 4; ++j)
            out[(size_t)qrow * DMODEL + head * HDIM + j * 16 + fr] = f2b(accO[j][r] * inv);
    }
}

// ---------------------------------------------------------------------------
// SiLU gate on bf16 g [SEQ][MLPD]: g[i,j] = silu(g[i,4096+j]) * g[i,j], j<4096.
// ---------------------------------------------------------------------------
__global__ void silu_bf16_kernel(unsigned short* __restrict__ g) {
    int idx = blockIdx.x * blockDim.x + threadIdx.x;
    if (idx >= SEQ * HALF_MLP / 4) return;
    const int i = idx >> 10;
    const int j = (idx & 1023) * 4;
    unsigned short* row = g + (size_t)i * MLPD;
    ushort4 a = *(const ushort4*)(row + j);
    ushort4 b = *(const ushort4*)(row + j + HALF_MLP);
    float x1[4] = { b2f(a.x), b2f(a.y), b2f(a.z), b2f(a.w) };
    float x2[4] = { b2f(b.x), b2f(b.y), b2f(b.z), b2f(b.w) };
    ushort4 o;
    unsigned short* op = (unsigned short*)&o;
#pragma unroll
    for (int t = 0; t < 4; ++t) {
        float sil = x2[t] / (1.0f + __expf(-x2[t]));
        op[t] = f2b(sil * x1[t]);
    }
    *(ushort4*)(row + j) = o;
}

// ---------------------------------------------------------------------------
extern "C" void kernel_launch(void* const* d_in, const int* in_sizes, int n_in,
                              void* d_out, int out_size, void* d_ws, size_t ws_size,
                              hipStream_t stream) {
    const float* x      = (const float*)d_in[0];
    const float* W_attn = (const float*)d_in[2];
    const float* W_out  = (const float*)d_in[3];
    const float* W_ffp  = (const float*)d_in[4];
    const float* W_ffo  = (const float*)d_in[5];
    float* out = (float*)d_out;

    // workspace layout
    char* wsb = (char*)d_ws;
    float*          qkv     = (float*)(wsb);                          // 24 MB fp32 [2048][3072]
    float*          h       = (float*)(wsb + (24u << 20));            //  8 MB fp32
    unsigned short* g       = (unsigned short*)(wsb + (32u << 20));   // 32 MB bf16 [2048][8192]
    unsigned short* xnb     = (unsigned short*)(wsb + (64u << 20));   //  4 MB bf16
    unsigned short* attnb   = (unsigned short*)(wsb + (68u << 20));   //  4 MB bf16
    unsigned short* wb_attn = (unsigned short*)(wsb + (72u << 20));   //  6 MB
    unsigned short* wb_out  = (unsigned short*)(wsb + (78u << 20));   //  2 MB
    unsigned short* wb_ffp  = (unsigned short*)(wsb + (80u << 20));   // 16 MB
    unsigned short* wb_ffo  = (unsigned short*)(wsb + (96u << 20));   //  8 MB
    unsigned short* Qp      = (unsigned short*)(wsb + (104u << 20));  //  4 MB bf16 [16][2048][64]
    unsigned short* Kp      = (unsigned short*)(wsb + (108u << 20));  //  4 MB
    unsigned short* Vt      = (unsigned short*)(wsb + (112u << 20));  //  4 MB bf16 [16][64][2048]

    // 0. weight conversions fp32 -> bf16
    {
        int n1 = 3 * DMODEL * DMODEL, n2 = DMODEL * DMODEL,
            n3 = MLPD * DMODEL, n4 = DMODEL * HALF_MLP;
        f2b_kernel<<<(n1 / 4 + 255) / 256, 256, 0, stream>>>(W_attn, wb_attn, n1);
        f2b_kernel<<<(n2 / 4 + 255) / 256, 256, 0, stream>>>(W_out,  wb_out,  n2);
        f2b_kernel<<<(n3 / 4 + 255) / 256, 256, 0, stream>>>(W_ffp,  wb_ffp,  n3);
        f2b_kernel<<<(n4 / 4 + 255) / 256, 256, 0, stream>>>(W_ffo,  wb_ffo,  n4);
    }

    // 1. xn = LN(x) -> bf16
    ln_kernel<<<SEQ, 256, 0, stream>>>(x, xnb);

    // 2. qkv = xn @ W_attn^T  (fp32 out)
    gemm_mfma<false, false><<<dim3(3 * DMODEL / 128, SEQ / 128), 256, 0, stream>>>(
        xnb, wb_attn, nullptr, qkv, DMODEL, DMODEL, 3 * DMODEL);

    // 3. pack q/k (rope+scale) and v (transpose) to bf16
    qkv_pack<<<dim3(SEQ / 64, NHEAD), 256, 0, stream>>>(qkv, Qp, Kp, Vt);

    // 4. MFMA flash attention -> bf16
    fattn_mfma<<<dim3(SEQ / 64, NHEAD), 256, 0, stream>>>(Qp, Kp, Vt, attnb);

    // 5. h = attn @ W_out^T + x  (fp32 out)
    gemm_mfma<true, false><<<dim3(DMODEL / 128, SEQ / 128), 256, 0, stream>>>(
        attnb, wb_out, x, h, DMODEL, DMODEL, DMODEL);

    // 6. hn = LN(h) -> bf16
    ln_kernel<<<SEQ, 256, 0, stream>>>(h, xnb);

    // 7. g = hn @ W_ffp^T  (bf16 out)
    gemm_mfma<false, true><<<dim3(MLPD / 128, SEQ / 128), 256, 0, stream>>>(
        xnb, wb_ffp, nullptr, g, DMODEL, DMODEL, MLPD);

    // 8. silu gate in place (bf16)
    silu_bf16_kernel<<<(SEQ * HALF_MLP / 4 + 255) / 256, 256, 0, stream>>>(g);

    // 9. out = act @ W_ffo^T + h  (fp32 out), A stride MLPD, K = 4096
    gemm_mfma<true, false><<<dim3(DMODEL / 128, SEQ / 128), 256, 0, stream>>>(
        g, wb_ffo, h, out, HALF_MLP, MLPD, DMODEL);
}

// Round 5
// 400.622 us; speedup vs baseline: 8.1215x; 1.1135x over previous
//
#include <hip/hip_runtime.h>
#include <math.h>

// Problem constants (from reference)
#define DMODEL 1024
#define NHEAD  16
#define HDIM   64
#define SEQ    2048
#define MLPD   8192
#define HALF_MLP 4096
static constexpr float LN_EPS_C = 1e-5f;
#define NEG_BIG (-1e30f)

typedef short bf16x8 __attribute__((ext_vector_type(8)));
typedef float f32x4  __attribute__((ext_vector_type(4)));

__device__ __forceinline__ unsigned short f2b(float f) {
    unsigned int u = __float_as_uint(f);
    u = (u + 0x7FFFu + ((u >> 16) & 1u)) >> 16;   // RNE
    return (unsigned short)u;
}
__device__ __forceinline__ float b2f(unsigned short h) {
    return __uint_as_float((unsigned int)h << 16);
}

__device__ __forceinline__ void async_copy16(const unsigned short* g, unsigned short* l) {
    __builtin_amdgcn_global_load_lds(
        (const __attribute__((address_space(1))) unsigned int*)(g),
        (__attribute__((address_space(3))) unsigned int*)(l),
        16, 0, 0);
}

// ---------------------------------------------------------------------------
// fp32 -> bf16 pack of ALL four weights in one launch.
// ---------------------------------------------------------------------------
__global__ void f2b_all(const float* __restrict__ a, const float* __restrict__ b,
                        const float* __restrict__ c, const float* __restrict__ d,
                        unsigned short* __restrict__ oa, unsigned short* __restrict__ ob,
                        unsigned short* __restrict__ oc, unsigned short* __restrict__ od) {
    const int n1 = 3 * DMODEL * DMODEL;
    const int n2 = n1 + DMODEL * DMODEL;
    const int n3 = n2 + MLPD * DMODEL;
    int i = (blockIdx.x * blockDim.x + threadIdx.x) * 4;
    const float* src; unsigned short* dst; int off;
    if (i < n1)      { src = a; dst = oa; off = i; }
    else if (i < n2) { src = b; dst = ob; off = i - n1; }
    else if (i < n3) { src = c; dst = oc; off = i - n2; }
    else             { src = d; dst = od; off = i - n3; }
    float4 v = *(const float4*)(src + off);
    ushort4 o;
    o.x = f2b(v.x); o.y = f2b(v.y); o.z = f2b(v.z); o.w = f2b(v.w);
    *(ushort4*)(dst + off) = o;
}

// ---------------------------------------------------------------------------
// LayerNorm -> bf16 out. One block (256 thr) per row.
// ---------------------------------------------------------------------------
__global__ void ln_kernel(const float* __restrict__ in, unsigned short* __restrict__ out) {
    const int row = blockIdx.x;
    const int tid = threadIdx.x;
    __shared__ float rs[256], rs2[256];
    const float* r = in + (size_t)row * DMODEL;
    float s = 0.f, s2 = 0.f;
    for (int i = tid; i < DMODEL; i += 256) {
        float v = r[i];
        s += v; s2 += v * v;
    }
    rs[tid] = s; rs2[tid] = s2;
    __syncthreads();
    for (int off = 128; off > 0; off >>= 1) {
        if (tid < off) { rs[tid] += rs[tid + off]; rs2[tid] += rs2[tid + off]; }
        __syncthreads();
    }
    float mu  = rs[0] * (1.0f / DMODEL);
    float var = rs2[0] * (1.0f / DMODEL) - mu * mu;
    float inv = rsqrtf(var + LN_EPS_C);
    for (int i = tid; i < DMODEL; i += 256)
        out[(size_t)row * DMODEL + i] = f2b((r[i] - mu) * inv);
}

// ---------------------------------------------------------------------------
// bf16 MFMA GEMM (m97 structure): C[M,N] = A[M,K] * B[N,K]^T, fp32 out.
// 128x128 tile, 256 thr = 4 waves (2x2), BK=32, global_load_lds staging.
// Used for the qkv projection only.
// ---------------------------------------------------------------------------
__global__ __launch_bounds__(256)
void gemm_mfma(const unsigned short* __restrict__ A, const unsigned short* __restrict__ B,
               float* __restrict__ C, int K, int lda, int ldc) {
    __shared__ unsigned short As[128 * 32];
    __shared__ unsigned short Bs[128 * 32];
    const int tid  = threadIdx.x;
    const int lane = tid & 63;
    const int w    = tid >> 6;
    const int wm   = w >> 1;
    const int wn   = w & 1;
    const int m0   = blockIdx.y * 128;
    const int n0   = blockIdx.x * 128;

    f32x4 acc[4][4] = {};

    const int srow = lane >> 2;
    const int scol = (lane & 3) * 8;
    const unsigned short* Abase = A + (size_t)(m0 + w * 32 + srow) * lda + scol;
    const unsigned short* Bbase = B + (size_t)(n0 + w * 32 + srow) * K + scol;
    unsigned short* AsW = &As[(w * 32) * 32];
    unsigned short* BsW = &Bs[(w * 32) * 32];

    const int fr = lane & 15;
    const int fk = (lane >> 4) * 8;

    for (int k0 = 0; k0 < K; k0 += 32) {
        async_copy16(Abase + k0,            AsW);
        async_copy16(Abase + k0 + 16 * lda, AsW + 16 * 32);
        async_copy16(Bbase + k0,            BsW);
        async_copy16(Bbase + k0 + 16 * (size_t)K, BsW + 16 * 32);
        __syncthreads();

        bf16x8 af[4], bfr[4];
#pragma unroll
        for (int i = 0; i < 4; ++i)
            af[i] = *(const bf16x8*)(&As[(wm * 64 + i * 16 + fr) * 32 + fk]);
#pragma unroll
        for (int j = 0; j < 4; ++j)
            bfr[j] = *(const bf16x8*)(&Bs[(wn * 64 + j * 16 + fr) * 32 + fk]);
#pragma unroll
        for (int i = 0; i < 4; ++i)
#pragma unroll
            for (int j = 0; j < 4; ++j)
                acc[i][j] = __builtin_amdgcn_mfma_f32_16x16x32_bf16(af[i], bfr[j], acc[i][j], 0, 0, 0);
        __syncthreads();
    }

    const int erow = (lane >> 4) * 4;
    const int ecol = lane & 15;
#pragma unroll
    for (int i = 0; i < 4; ++i)
#pragma unroll
        for (int j = 0; j < 4; ++j) {
            const int colg = n0 + wn * 64 + j * 16 + ecol;
#pragma unroll
            for (int r = 0; r < 4; ++r) {
                const int rowg = m0 + wm * 64 + i * 16 + erow + r;
                C[(size_t)rowg * ldc + colg] = acc[i][j][r];
            }
        }
}

// ---------------------------------------------------------------------------
// Split-K bf16 MFMA GEMM: partial[z][M][N] (fp32) = A[:,z*Ksub:+Ksub] * B^T.
// Grid (N/128, M/128, nsplit). ldb = full K (B row stride).
// ---------------------------------------------------------------------------
__global__ __launch_bounds__(256)
void gemm_mfma_sk(const unsigned short* __restrict__ A, const unsigned short* __restrict__ B,
                  float* __restrict__ P, int Ksub, int lda, int ldb, int ldc) {
    __shared__ unsigned short As[128 * 32];
    __shared__ unsigned short Bs[128 * 32];
    const int tid  = threadIdx.x;
    const int lane = tid & 63;
    const int w    = tid >> 6;
    const int wm   = w >> 1;
    const int wn   = w & 1;
    const int m0   = blockIdx.y * 128;
    const int n0   = blockIdx.x * 128;
    const int kb   = blockIdx.z * Ksub;

    f32x4 acc[4][4] = {};

    const int srow = lane >> 2;
    const int scol = (lane & 3) * 8;
    const unsigned short* Abase = A + (size_t)(m0 + w * 32 + srow) * lda + scol + kb;
    const unsigned short* Bbase = B + (size_t)(n0 + w * 32 + srow) * ldb + scol + kb;
    unsigned short* AsW = &As[(w * 32) * 32];
    unsigned short* BsW = &Bs[(w * 32) * 32];

    const int fr = lane & 15;
    const int fk = (lane >> 4) * 8;

    for (int k0 = 0; k0 < Ksub; k0 += 32) {
        async_copy16(Abase + k0,            AsW);
        async_copy16(Abase + k0 + 16 * lda, AsW + 16 * 32);
        async_copy16(Bbase + k0,            BsW);
        async_copy16(Bbase + k0 + 16 * (size_t)ldb, BsW + 16 * 32);
        __syncthreads();

        bf16x8 af[4], bfr[4];
#pragma unroll
        for (int i = 0; i < 4; ++i)
            af[i] = *(const bf16x8*)(&As[(wm * 64 + i * 16 + fr) * 32 + fk]);
#pragma unroll
        for (int j = 0; j < 4; ++j)
            bfr[j] = *(const bf16x8*)(&Bs[(wn * 64 + j * 16 + fr) * 32 + fk]);
#pragma unroll
        for (int i = 0; i < 4; ++i)
#pragma unroll
            for (int j = 0; j < 4; ++j)
                acc[i][j] = __builtin_amdgcn_mfma_f32_16x16x32_bf16(af[i], bfr[j], acc[i][j], 0, 0, 0);
        __syncthreads();
    }

    float* Pp = P + (size_t)blockIdx.z * SEQ * ldc;
    const int erow = (lane >> 4) * 4;
    const int ecol = lane & 15;
#pragma unroll
    for (int i = 0; i < 4; ++i)
#pragma unroll
        for (int j = 0; j < 4; ++j) {
            const int colg = n0 + wn * 64 + j * 16 + ecol;
#pragma unroll
            for (int r = 0; r < 4; ++r) {
                const int rowg = m0 + wm * 64 + i * 16 + erow + r;
                Pp[(size_t)rowg * ldc + colg] = acc[i][j][r];
            }
        }
}

// ---------------------------------------------------------------------------
// Split-K reducers (+ fp32 residual), float4-vectorized.
// ---------------------------------------------------------------------------
__global__ void reduce2_kernel(const float* __restrict__ p0, const float* __restrict__ p1,
                               const float* __restrict__ res, float* __restrict__ out) {
    int i = (blockIdx.x * blockDim.x + threadIdx.x) * 4;
    float4 a = *(const float4*)(p0 + i);
    float4 b = *(const float4*)(p1 + i);
    float4 r = *(const float4*)(res + i);
    float4 o = { a.x + b.x + r.x, a.y + b.y + r.y, a.z + b.z + r.z, a.w + b.w + r.w };
    *(float4*)(out + i) = o;
}

__global__ void reduce4_kernel(const float* __restrict__ p0, const float* __restrict__ p1,
                               const float* __restrict__ p2, const float* __restrict__ p3,
                               const float* __restrict__ res, float* __restrict__ out) {
    int i = (blockIdx.x * blockDim.x + threadIdx.x) * 4;
    float4 a = *(const float4*)(p0 + i);
    float4 b = *(const float4*)(p1 + i);
    float4 c = *(const float4*)(p2 + i);
    float4 d = *(const float4*)(p3 + i);
    float4 r = *(const float4*)(res + i);
    float4 o = { a.x + b.x + c.x + d.x + r.x, a.y + b.y + c.y + d.y + r.y,
                 a.z + b.z + c.z + d.z + r.z, a.w + b.w + c.w + d.w + r.w };
    *(float4*)(out + i) = o;
}

// ---------------------------------------------------------------------------
// Fused FFN-up + SiLU gate. One block computes C1 = A*Wffp[n0:+128]^T and
// C2 = A*Wffp[4096+n0:+128]^T (shared A tile), writes silu(C2)*C1 as bf16
// to gact[M][4096]. Grid (4096/128, SEQ/128).
// ---------------------------------------------------------------------------
__global__ __launch_bounds__(256)
void gemm_ffp_silu(const unsigned short* __restrict__ A, const unsigned short* __restrict__ B,
                   unsigned short* __restrict__ gact) {
    __shared__ unsigned short As[128 * 32];
    __shared__ unsigned short B1s[128 * 32];
    __shared__ unsigned short B2s[128 * 32];
    const int tid  = threadIdx.x;
    const int lane = tid & 63;
    const int w    = tid >> 6;
    const int wm   = w >> 1;
    const int wn   = w & 1;
    const int m0   = blockIdx.y * 128;
    const int n0   = blockIdx.x * 128;

    f32x4 acc1[4][4] = {};
    f32x4 acc2[4][4] = {};

    const int srow = lane >> 2;
    const int scol = (lane & 3) * 8;
    const unsigned short* Abase  = A + (size_t)(m0 + w * 32 + srow) * DMODEL + scol;
    const unsigned short* B1base = B + (size_t)(n0 + w * 32 + srow) * DMODEL + scol;
    const unsigned short* B2base = B + (size_t)(HALF_MLP + n0 + w * 32 + srow) * DMODEL + scol;
    unsigned short* AsW  = &As[(w * 32) * 32];
    unsigned short* B1sW = &B1s[(w * 32) * 32];
    unsigned short* B2sW = &B2s[(w * 32) * 32];

    const int fr = lane & 15;
    const int fk = (lane >> 4) * 8;

    for (int k0 = 0; k0 < DMODEL; k0 += 32) {
        async_copy16(Abase  + k0,               AsW);
        async_copy16(Abase  + k0 + 16 * DMODEL, AsW + 16 * 32);
        async_copy16(B1base + k0,               B1sW);
        async_copy16(B1base + k0 + 16 * DMODEL, B1sW + 16 * 32);
        async_copy16(B2base + k0,               B2sW);
        async_copy16(B2base + k0 + 16 * DMODEL, B2sW + 16 * 32);
        __syncthreads();

        bf16x8 af[4], b1[4], b2[4];
#pragma unroll
        for (int i = 0; i < 4; ++i)
            af[i] = *(const bf16x8*)(&As[(wm * 64 + i * 16 + fr) * 32 + fk]);
#pragma unroll
        for (int j = 0; j < 4; ++j) {
            b1[j] = *(const bf16x8*)(&B1s[(wn * 64 + j * 16 + fr) * 32 + fk]);
            b2[j] = *(const bf16x8*)(&B2s[(wn * 64 + j * 16 + fr) * 32 + fk]);
        }
#pragma unroll
        for (int i = 0; i < 4; ++i)
#pragma unroll
            for (int j = 0; j < 4; ++j) {
                acc1[i][j] = __builtin_amdgcn_mfma_f32_16x16x32_bf16(af[i], b1[j], acc1[i][j], 0, 0, 0);
                acc2[i][j] = __builtin_amdgcn_mfma_f32_16x16x32_bf16(af[i], b2[j], acc2[i][j], 0, 0, 0);
            }
        __syncthreads();
    }

    const int erow = (lane >> 4) * 4;
    const int ecol = lane & 15;
#pragma unroll
    for (int i = 0; i < 4; ++i)
#pragma unroll
        for (int j = 0; j < 4; ++j) {
            const int colg = n0 + wn * 64 + j * 16 + ecol;
#pragma unroll
            for (int r = 0; r < 4; ++r) {
                const int rowg = m0 + wm * 64 + i * 16 + erow + r;
                float x1 = acc1[i][j][r];
                float x2 = acc2[i][j][r];
                float sil = x2 / (1.0f + __expf(-x2));
                gact[(size_t)rowg * HALF_MLP + colg] = f2b(sil * x1);
            }
        }
}

// ---------------------------------------------------------------------------
// QKV pack: rope+scale q,k -> bf16 Qp/Kp [H][S][64]; transpose v -> Vt [H][64][S].
// ---------------------------------------------------------------------------
__global__ void qkv_pack(const float* __restrict__ qkv,
                         unsigned short* __restrict__ Qp,
                         unsigned short* __restrict__ Kp,
                         unsigned short* __restrict__ Vt) {
    const int head = blockIdx.y;
    const int m0   = blockIdx.x * 64;
    const int tid  = threadIdx.x;
    const int r    = tid >> 2;
    const int c    = (tid & 3) * 16;

    __shared__ float Vl[64][65];

    const float* base = qkv + (size_t)(m0 + r) * (3 * DMODEL) + head * HDIM;

#pragma unroll
    for (int u = 0; u < 4; ++u) {
        float4 v = *(const float4*)(base + 2 * DMODEL + c + u * 4);
        Vl[r][c + u * 4 + 0] = v.x; Vl[r][c + u * 4 + 1] = v.y;
        Vl[r][c + u * 4 + 2] = v.z; Vl[r][c + u * 4 + 3] = v.w;
    }

    const float pos = (float)(m0 + r);
    unsigned short qo[16], ko[16];
#pragma unroll
    for (int u = 0; u < 16; ++u) {
        const int d = c + u;
        const int p = d & 31;
        const float inv_freq = powf(10000.0f, -(float)p / 32.0f);
        const float ang = pos * inv_freq;
        const float cs = cosf(ang), sn = sinf(ang);
        const float sgn = (d < 32) ? -1.0f : 1.0f;
        float q1 = base[d], q2 = base[d ^ 32];
        float k1 = base[DMODEL + d], k2 = base[DMODEL + (d ^ 32)];
        qo[u] = f2b((q1 * cs + sgn * q2 * sn) * 0.125f);
        ko[u] = f2b(k1 * cs + sgn * k2 * sn);
    }
    {
        unsigned short* qdst = Qp + ((size_t)head * SEQ + m0 + r) * HDIM + c;
        unsigned short* kdst = Kp + ((size_t)head * SEQ + m0 + r) * HDIM + c;
#pragma unroll
        for (int u = 0; u < 2; ++u) {
            *(bf16x8*)(qdst + u * 8) = *(bf16x8*)(&qo[u * 8]);
            *(bf16x8*)(kdst + u * 8) = *(bf16x8*)(&ko[u * 8]);
        }
    }

    __syncthreads();

    unsigned short vo[16];
#pragma unroll
    for (int u = 0; u < 16; ++u) vo[u] = f2b(Vl[c + u][r]);
    unsigned short* vdst = Vt + ((size_t)head * HDIM + r) * SEQ + m0 + c;
#pragma unroll
    for (int u = 0; u < 2; ++u)
        *(bf16x8*)(vdst + u * 8) = *(bf16x8*)(&vo[u * 8]);
}

// ---------------------------------------------------------------------------
// MFMA flash attention. One block per (64-row Q tile, head); 4 waves.
// ---------------------------------------------------------------------------
#define LDQ 72
__global__ __launch_bounds__(256)
void fattn_mfma(const unsigned short* __restrict__ Qp,
                const unsigned short* __restrict__ Kp,
                const unsigned short* __restrict__ Vt,
                unsigned short* __restrict__ out) {
    const int head = blockIdx.y;
    const int bx   = blockIdx.x;
    const int mt   = (bx & 1) ? (31 - (bx >> 1)) : (bx >> 1);
    const int m0   = mt * 64;
    const int tid  = threadIdx.x;
    const int lane = tid & 63;
    const int w    = tid >> 6;
    const int fr   = lane & 15;
    const int quad = lane >> 4;

    __shared__ unsigned short Qs[64 * LDQ];
    __shared__ unsigned short Ks[64 * LDQ];
    __shared__ unsigned short Vs[64 * LDQ];
    __shared__ unsigned short Ps[64 * LDQ];

    const unsigned short* Qg = Qp + ((size_t)head * SEQ + m0) * HDIM;
    const unsigned short* Kg = Kp + (size_t)head * SEQ * HDIM;
    const unsigned short* Vg = Vt + (size_t)head * HDIM * SEQ;

    const int sr = tid >> 2;
    const int sc = (tid & 3) * 16;

    {
        bf16x8 a = *(const bf16x8*)(Qg + sr * HDIM + sc);
        bf16x8 b = *(const bf16x8*)(Qg + sr * HDIM + sc + 8);
        *(bf16x8*)(&Qs[sr * LDQ + sc]) = a;
        *(bf16x8*)(&Qs[sr * LDQ + sc + 8]) = b;
    }

    f32x4 accO[4] = {};
    float m_i[4], l_i[4];
#pragma unroll
    for (int r = 0; r < 4; ++r) { m_i[r] = NEG_BIG; l_i[r] = 0.f; }

    for (int j0 = 0; j0 <= m0; j0 += 64) {
        __syncthreads();
        {
            bf16x8 k1 = *(const bf16x8*)(Kg + (size_t)(j0 + sr) * HDIM + sc);
            bf16x8 k2 = *(const bf16x8*)(Kg + (size_t)(j0 + sr) * HDIM + sc + 8);
            bf16x8 v1 = *(const bf16x8*)(Vg + (size_t)sr * SEQ + j0 + sc);
            bf16x8 v2 = *(const bf16x8*)(Vg + (size_t)sr * SEQ + j0 + sc + 8);
            *(bf16x8*)(&Ks[sr * LDQ + sc]) = k1;
            *(bf16x8*)(&Ks[sr * LDQ + sc + 8]) = k2;
            *(bf16x8*)(&Vs[sr * LDQ + sc]) = v1;
            *(bf16x8*)(&Vs[sr * LDQ + sc + 8]) = v2;
        }
        __syncthreads();

        f32x4 accS[4] = {};
#pragma unroll
        for (int kk = 0; kk < 64; kk += 32) {
            bf16x8 af = *(const bf16x8*)(&Qs[(w * 16 + fr) * LDQ + kk + quad * 8]);
#pragma unroll
            for (int j = 0; j < 4; ++j) {
                bf16x8 bf_ = *(const bf16x8*)(&Ks[(j * 16 + fr) * LDQ + kk + quad * 8]);
                accS[j] = __builtin_amdgcn_mfma_f32_16x16x32_bf16(af, bf_, accS[j], 0, 0, 0);
            }
        }

        if (j0 == m0) {
#pragma unroll
            for (int j = 0; j < 4; ++j)
#pragma unroll
                for (int r = 0; r < 4; ++r)
                    if (j * 16 + fr > w * 16 + quad * 4 + r) accS[j][r] = NEG_BIG;
        }

        float rmax[4];
#pragma unroll
        for (int r = 0; r < 4; ++r)
            rmax[r] = fmaxf(fmaxf(accS[0][r], accS[1][r]), fmaxf(accS[2][r], accS[3][r]));
#pragma unroll
        for (int off = 1; off < 16; off <<= 1)
#pragma unroll
            for (int r = 0; r < 4; ++r)
                rmax[r] = fmaxf(rmax[r], __shfl_xor(rmax[r], off));

        float alpha[4], rsum[4];
#pragma unroll
        for (int r = 0; r < 4; ++r) {
            float mn = fmaxf(m_i[r], rmax[r]);
            alpha[r] = __expf(m_i[r] - mn);
            m_i[r] = mn;
            rsum[r] = 0.f;
        }
#pragma unroll
        for (int j = 0; j < 4; ++j)
#pragma unroll
            for (int r = 0; r < 4; ++r) {
                float p = __expf(accS[j][r] - m_i[r]);
                accS[j][r] = p;
                rsum[r] += p;
            }
#pragma unroll
        for (int off = 1; off < 16; off <<= 1)
#pragma unroll
            for (int r = 0; r < 4; ++r)
                rsum[r] += __shfl_xor(rsum[r], off);
#pragma unroll
        for (int r = 0; r < 4; ++r) {
            l_i[r] = l_i[r] * alpha[r] + rsum[r];
#pragma unroll
            for (int j = 0; j < 4; ++j) accO[j][r] *= alpha[r];
        }

#pragma unroll
        for (int j = 0; j < 4; ++j)
#pragma unroll
            for (int r = 0; r < 4; ++r)
                Ps[(w * 16 + quad * 4 + r) * LDQ + j * 16 + fr] = f2b(accS[j][r]);

#pragma unroll
        for (int kk = 0; kk < 64; kk += 32) {
            bf16x8 af = *(const bf16x8*)(&Ps[(w * 16 + fr) * LDQ + kk + quad * 8]);
#pragma unroll
            for (int j = 0; j < 4; ++j) {
                bf16x8 bf_ = *(const bf16x8*)(&Vs[(j * 16 + fr) * LDQ + kk + quad * 8]);
                accO[j] = __builtin_amdgcn_mfma_f32_16x16x32_bf16(af, bf_, accO[j], 0, 0, 0);
            }
        }
    }

#pragma unroll
    for (int r = 0; r < 4; ++r) {
        const float inv = 1.0f / l_i[r];
        const int qrow = m0 + w * 16 + quad * 4 + r;
#pragma unroll
        for (int j = 0; j < 4; ++j)
            out[(size_t)qrow * DMODEL + head * HDIM + j * 16 + fr] = f2b(accO[j][r] * inv);
    }
}

// ---------------------------------------------------------------------------
extern "C" void kernel_launch(void* const* d_in, const int* in_sizes, int n_in,
                              void* d_out, int out_size, void* d_ws, size_t ws_size,
                              hipStream_t stream) {
    const float* x      = (const float*)d_in[0];
    const float* W_attn = (const float*)d_in[2];
    const float* W_out  = (const float*)d_in[3];
    const float* W_ffp  = (const float*)d_in[4];
    const float* W_ffo  = (const float*)d_in[5];
    float* out = (float*)d_out;

    // workspace layout (100 MB total)
    char* wsb = (char*)d_ws;
    unsigned short* wb_attn = (unsigned short*)(wsb);                 // [0,6)
    unsigned short* wb_out  = (unsigned short*)(wsb + (6u  << 20));   // [6,8)
    unsigned short* wb_ffp  = (unsigned short*)(wsb + (8u  << 20));   // [8,24)
    unsigned short* wb_ffo  = (unsigned short*)(wsb + (24u << 20));   // [24,32)
    unsigned short* xnb     = (unsigned short*)(wsb + (32u << 20));   // [32,36) bf16 [2048][1024]
    float*          qkv     = (float*)(wsb + (36u << 20));            // [36,60) fp32 [2048][3072]
    unsigned short* Qp      = (unsigned short*)(wsb + (60u << 20));   // [60,64)
    unsigned short* Kp      = (unsigned short*)(wsb + (64u << 20));   // [64,68)
    unsigned short* Vt      = (unsigned short*)(wsb + (68u << 20));   // [68,72)
    unsigned short* attnb   = (unsigned short*)(wsb + (72u << 20));   // [72,76)
    float*          h       = (float*)(wsb + (76u << 20));            // [76,84) fp32
    unsigned short* gact    = (unsigned short*)(wsb + (84u << 20));   // [84,100) bf16 [2048][4096]
    // split-K partial planes (8 MB each), reusing dead regions:
    float* wout_p = (float*)(wsb + (36u << 20));   // step 5: qkv dead -> 2 planes [36,52)
    float* ffo_p  = (float*)(wsb + (32u << 20));   // step 8: xnb/qkv/Qp dead -> 4 planes [32,64)

    // 0. all weights fp32 -> bf16 (one launch)
    {
        int total = (3 * DMODEL * DMODEL + DMODEL * DMODEL + MLPD * DMODEL + DMODEL * HALF_MLP) / 4;
        f2b_all<<<total / 256, 256, 0, stream>>>(W_attn, W_out, W_ffp, W_ffo,
                                                 wb_attn, wb_out, wb_ffp, wb_ffo);
    }

    // 1. xn = LN(x) -> bf16
    ln_kernel<<<SEQ, 256, 0, stream>>>(x, xnb);

    // 2. qkv = xn @ W_attn^T  (fp32 out)
    gemm_mfma<<<dim3(3 * DMODEL / 128, SEQ / 128), 256, 0, stream>>>(
        xnb, wb_attn, qkv, DMODEL, DMODEL, 3 * DMODEL);

    // 3. pack q/k (rope+scale) and v (transpose) to bf16
    qkv_pack<<<dim3(SEQ / 64, NHEAD), 256, 0, stream>>>(qkv, Qp, Kp, Vt);

    // 4. MFMA flash attention -> bf16
    fattn_mfma<<<dim3(SEQ / 64, NHEAD), 256, 0, stream>>>(Qp, Kp, Vt, attnb);

    // 5. h = attn @ W_out^T + x  (split-K=2 into dead qkv region, then reduce)
    gemm_mfma_sk<<<dim3(DMODEL / 128, SEQ / 128, 2), 256, 0, stream>>>(
        attnb, wb_out, wout_p, DMODEL / 2, DMODEL, DMODEL, DMODEL);
    reduce2_kernel<<<SEQ * DMODEL / 4 / 256, 256, 0, stream>>>(
        wout_p, wout_p + (size_t)SEQ * DMODEL, x, h);

    // 6. hn = LN(h) -> bf16
    ln_kernel<<<SEQ, 256, 0, stream>>>(h, xnb);

    // 7. gact = silu(hn @ Wffp2^T) * (hn @ Wffp1^T)  (fused, bf16 out)
    gemm_ffp_silu<<<dim3(HALF_MLP / 128, SEQ / 128), 256, 0, stream>>>(
        xnb, wb_ffp, gact);

    // 8. out = gact @ W_ffo^T + h  (split-K=4 into dead xnb/qkv/Qp region, reduce)
    gemm_mfma_sk<<<dim3(DMODEL / 128, SEQ / 128, 4), 256, 0, stream>>>(
        gact, wb_ffo, ffo_p, HALF_MLP / 4, HALF_MLP, HALF_MLP, DMODEL);
    reduce4_kernel<<<SEQ * DMODEL / 4 / 256, 256, 0, stream>>>(
        ffo_p, ffo_p + (size_t)SEQ * DMODEL, ffo_p + 2 * (size_t)SEQ * DMODEL,
        ffo_p + 3 * (size_t)SEQ * DMODEL, h, out);
}